// Round 7
// baseline (341.070 us; speedup 1.0000x reference)
//
#include <hip/hip_runtime.h>
#include <hip/hip_bf16.h>

// Problem constants
#define Bq   16
#define Nq   1024
#define Cq   256
#define NHq  8
#define DHq  32
#define HIDq 1024
#define BNq  (Bq * Nq)   // 16384 tokens

typedef float f32x4 __attribute__((ext_vector_type(4)));
typedef short bf16x8 __attribute__((ext_vector_type(8)));
typedef unsigned short ushort_t;

#define VMW6()  asm volatile("s_waitcnt vmcnt(6)" ::: "memory")
#define VMW0()  asm volatile("s_waitcnt vmcnt(0)" ::: "memory")

__device__ __forceinline__ unsigned int f2bf(float f) {   // RNE
    unsigned int u = __builtin_bit_cast(unsigned int, f);
    u = (u + 0x7fffu + ((u >> 16) & 1u)) >> 16;
    return u & 0xffffu;
}
// pack two floats -> two bf16 (round-half-up) in one dword via v_perm
__device__ __forceinline__ unsigned int packbf2(float a, float b) {
    unsigned int ua = __builtin_bit_cast(unsigned int, a) + 0x8000u;
    unsigned int ub = __builtin_bit_cast(unsigned int, b) + 0x8000u;
    return __builtin_amdgcn_perm(ub, ua, 0x07060302);
}
// single-instruction packed f32x2 -> bf16x2 (RNE); lo -> low half
__device__ __forceinline__ unsigned int cvtpk_bf16(float lo, float hi) {
    unsigned int r;
    asm("v_cvt_pk_bf16_f32 %0, %1, %2" : "=v"(r) : "v"(lo), "v"(hi));
    return r;
}
// branch-free tanh-approx GELU
__device__ __forceinline__ float gelu_t(float x) {
    float y = x * (0.7978845608028654f + 0.035677408136300125f * x * x);
    float e = __builtin_amdgcn_exp2f(y * 2.8853900817779268f);
    return x - x / (1.f + e);
}

typedef __attribute__((address_space(1))) const unsigned int* gas_u32;
typedef __attribute__((address_space(3))) unsigned int* las_u32;
__device__ __forceinline__ void gload16(const void* g, void* l) {
    __builtin_amdgcn_global_load_lds((gas_u32)g, (las_u32)l, 16, 0, 0);
}

// ---------------------------------------------------------------------------
// Fused fp32 -> bf16 casts: 9 segments in one dispatch.
// ---------------------------------------------------------------------------
struct CastSeg { const float* src; ushort_t* dst; int nblk; int n; };
struct CastArgs { CastSeg s[9]; };

__global__ __launch_bounds__(256) void castm(CastArgs a) {
    int bid = blockIdx.x;
    int seg = 0, acc = 0;
    for (seg = 0; seg < 9; seg++) {
        if (bid < acc + a.s[seg].nblk) break;
        acc += a.s[seg].nblk;
    }
    const CastSeg sg = a.s[seg];
    int i = (bid - acc) * 1024 + threadIdx.x * 4;
    if (i < sg.n) {
        float4 v = *(const float4*)(sg.src + i);
        uint2 u;
        u.x = packbf2(v.x, v.y);
        u.y = packbf2(v.z, v.w);
        *(uint2*)(sg.dst + i) = u;
    }
}

// ---------------------------------------------------------------------------
// LayerNorm over C=256 -> bf16. One wave per token, 4 tokens per block.
// ---------------------------------------------------------------------------
__global__ __launch_bounds__(256) void ln_kernel(const float* __restrict__ X,
                                                 const float* __restrict__ w,
                                                 const float* __restrict__ b,
                                                 ushort_t* __restrict__ Y) {
    int wave = threadIdx.x >> 6, lane = threadIdx.x & 63;
    int t = blockIdx.x * 4 + wave;
    float4 v = *(const float4*)(X + (size_t)t * Cq + lane * 4);
    float s = v.x + v.y + v.z + v.w;
#pragma unroll
    for (int d = 1; d < 64; d <<= 1) s += __shfl_xor(s, d);
    float mean = s * (1.f / 256.f);
    float4 dv = {v.x - mean, v.y - mean, v.z - mean, v.w - mean};
    float q = dv.x * dv.x + dv.y * dv.y + dv.z * dv.z + dv.w * dv.w;
#pragma unroll
    for (int d = 1; d < 64; d <<= 1) q += __shfl_xor(q, d);
    float rs = rsqrtf(q * (1.f / 256.f) + 1e-5f);
    float4 wv = *(const float4*)(w + lane * 4);
    float4 bv = *(const float4*)(b + lane * 4);
    uint2 u;
    u.x = packbf2(dv.x * rs * wv.x + bv.x, dv.y * rs * wv.y + bv.y);
    u.y = packbf2(dv.z * rs * wv.z + bv.z, dv.w * rs * wv.w + bv.w);
    *(uint2*)(Y + (size_t)t * Cq + lane * 4) = u;
}

// ---------------------------------------------------------------------------
// MFMA GEMM: multi-tile persistent blocks + 2-buffer counted-vmcnt pipeline.
// A block owns NTILES consecutive m-panels (128 rows each) at ONE n-panel
// (64 cols) -> W-panel stays L2-hot across its tiles, and the K-pipeline
// NEVER drains across tile boundaries: TOT = NTILES*(KT/64) flattened steps,
// ONE prologue fill per block (vs one per tile before), grid small enough
// that ALL blocks are co-resident (single generation, no ramp).
// Per step s (cur=s&1): ds_read 12 frags(cur) -> lgkm(0) -> barrier ->
// STAGE(cur, s+2) -> 16 MFMA -> vmcnt(6) [waits only step s+1's loads,
// issued a full step earlier] -> barrier. Epilogue fires every NT steps
// after the wait (its stores only ADD to vmcnt -> waits stay conservative).
// LDS: 2 x (A 16KB + B 8KB) = 48KB. Fragment-ordered chunks: chunk c (0..7)
// holds k=(c&3)*8+(c>>2)*32; wave w stages chunks {w, w+4}. Wave w owns rows
// [w*32, w*32+32). MFMA operands swapped (C^T).
// OMODE 0: fp32 out (+bias/GELU/residual); OMODE 1: qkv -> bf16 head-major
//          (Q scaled by rsqrt(32)*log2e, V transposed [bh][32][1024]);
// OMODE 2: bf16 out; OMODE 3: fused off/aw (ng<64 -> OffB w/ bias, else AwB
//          w/ R-as-bias; AwB = OutP + BN*64).
// ---------------------------------------------------------------------------
template <int OMODE, bool GELU_, bool RESID, int KT, int NTILES>
__global__ __launch_bounds__(256) void mgemm(const ushort_t* __restrict__ A,
                                             const ushort_t* __restrict__ W,
                                             const float* __restrict__ bias,
                                             const float* __restrict__ R,
                                             void* __restrict__ OutP,
                                             int M, int Nn) {
    __shared__ __align__(16) ushort_t Al[2][8192];
    __shared__ __align__(16) ushort_t Bl[2][4096];
    constexpr int NT = KT / 64;          // K-steps per tile
    constexpr int TOT = NT * NTILES;     // flattened pipeline length
    int m_base = blockIdx.x * (128 * NTILES), n0 = blockIdx.y * 64;
    int tid = threadIdx.x;
    int w = tid >> 6, lane = tid & 63;
    int l15 = lane & 15, quad = lane >> 4;

    f32x4 acc[2][4];
#pragma unroll
    for (int i = 0; i < 2; i++)
#pragma unroll
        for (int j = 0; j < 4; j++) acc[i][j] = (f32x4){0.f, 0.f, 0.f, 0.f};

    const ushort_t* gA0 = A + (size_t)(m_base + lane) * KT + w * 8;
    const ushort_t* gA1 = gA0 + (size_t)64 * KT;
    const ushort_t* gB0 = W + (size_t)(n0 + lane) * KT + w * 8;

    // STAGE for flattened step u: tile = u/NT (m advances), k = (u%NT)*64.
    auto STAGE = [&](int buf, int u) {
        const size_t aoff = (size_t)(u / NT) * 128 * KT + (u % NT) * 64;
        const int k0 = (u % NT) * 64;
        gload16(gA0 + aoff,      &Al[buf][w * 1024]);
        gload16(gA1 + aoff,      &Al[buf][w * 1024 + 512]);
        gload16(gA0 + aoff + 32, &Al[buf][(w + 4) * 1024]);
        gload16(gA1 + aoff + 32, &Al[buf][(w + 4) * 1024 + 512]);
        gload16(gB0 + k0,        &Bl[buf][w * 512]);
        gload16(gB0 + k0 + 32,   &Bl[buf][(w + 4) * 512]);
    };

    // Epilogue for one finished tile; then caller resets acc.
    auto EPI = [&](int tile) {
#pragma unroll
        for (int i = 0; i < 2; i++) {
            int mg = m_base + tile * 128 + w * 32 + i * 16 + l15;
#pragma unroll
            for (int j = 0; j < 4; j++) {
                int ng = n0 + j * 16 + quad * 4;
                f32x4 rv = acc[i][j];
                if constexpr (OMODE == 1) {
                    int which = ng >> 8;
                    int h = (ng >> 5) & 7;
                    int d = ng & 31;
                    int bb = mg >> 10, nn = mg & 1023;
                    ushort_t* qb = (ushort_t*)OutP;
                    if (which == 2) {          // V transposed: [bh][d][n]
                        size_t dst = 2 * (size_t)BNq * Cq +
                                     ((size_t)(bb * 8 + h) * 32 + d) * 1024 + nn;
#pragma unroll
                        for (int r = 0; r < 4; r++)
                            qb[dst + (size_t)r * 1024] = (ushort_t)f2bf(rv[r]);
                    } else {
                        if (which == 0) {
                            const float sc = 0.17677669529663687f * 1.4426950408889634f;
                            rv[0] *= sc; rv[1] *= sc; rv[2] *= sc; rv[3] *= sc;
                        }
                        size_t dst = (size_t)which * ((size_t)BNq * Cq) +
                                     ((size_t)(bb * 8 + h) * 1024 + nn) * 32 + d;
                        uint2 pk;
                        pk.x = packbf2(rv[0], rv[1]);
                        pk.y = packbf2(rv[2], rv[3]);
                        *(uint2*)(qb + dst) = pk;
                    }
                } else if constexpr (OMODE == 3) {
                    if (ng >= 96) continue;
                    if (ng < 64) {
                        float4 bv = *(const float4*)(bias + ng);
                        rv[0] += bv.x; rv[1] += bv.y; rv[2] += bv.z; rv[3] += bv.w;
                        *(float4*)((float*)OutP + (size_t)mg * 64 + ng) =
                            make_float4(rv[0], rv[1], rv[2], rv[3]);
                    } else {
                        float4 bv = *(const float4*)(R + (ng - 64));
                        rv[0] += bv.x; rv[1] += bv.y; rv[2] += bv.z; rv[3] += bv.w;
                        *(float4*)((float*)OutP + (size_t)BNq * 64 + (size_t)mg * 32 + (ng - 64)) =
                            make_float4(rv[0], rv[1], rv[2], rv[3]);
                    }
                } else {
                    if (bias) {
                        float4 bv = *(const float4*)(bias + ng);
                        rv[0] += bv.x; rv[1] += bv.y; rv[2] += bv.z; rv[3] += bv.w;
                    }
                    if (GELU_) {
#pragma unroll
                        for (int r = 0; r < 4; r++) rv[r] = gelu_t(rv[r]);
                    }
                    if constexpr (OMODE == 2) {
                        uint2 pk;
                        pk.x = packbf2(rv[0], rv[1]);
                        pk.y = packbf2(rv[2], rv[3]);
                        *(uint2*)((ushort_t*)OutP + (size_t)mg * Nn + ng) = pk;
                    } else {
                        if (RESID) {
                            float4 rr = *(const float4*)(R + (size_t)mg * Nn + ng);
                            rv[0] += rr.x; rv[1] += rr.y; rv[2] += rr.z; rv[3] += rr.w;
                        }
                        *(float4*)((float*)OutP + (size_t)mg * Nn + ng) =
                            make_float4(rv[0], rv[1], rv[2], rv[3]);
                    }
                }
            }
        }
    };

    // prologue: fill 2-deep, wait only for step 0's group
    STAGE(0, 0);
    STAGE(1, 1);
    VMW6();
    __builtin_amdgcn_s_barrier();

#pragma unroll
    for (int s = 0; s < TOT; s++) {
        const int cur = s & 1;
        bf16x8 aF[2][2], bF[2][4];
#pragma unroll
        for (int ks = 0; ks < 2; ks++) {
#pragma unroll
            for (int i = 0; i < 2; i++)
                aF[ks][i] = *(const bf16x8*)&Al[cur][(ks * 4 + quad) * 1024 + (w * 32 + i * 16 + l15) * 8];
#pragma unroll
            for (int j = 0; j < 4; j++)
                bF[ks][j] = *(const bf16x8*)&Bl[cur][(ks * 4 + quad) * 512 + (j * 16 + l15) * 8];
        }
        asm volatile("s_waitcnt lgkmcnt(0)" ::: "memory");
        __builtin_amdgcn_sched_barrier(0);
        __builtin_amdgcn_s_barrier();        // all waves done reading buf cur
        if (s + 2 < TOT) STAGE(cur, s + 2);  // overwrite freed buffer

        __builtin_amdgcn_s_setprio(1);
#pragma unroll
        for (int ks = 0; ks < 2; ks++)
#pragma unroll
            for (int i = 0; i < 2; i++)
#pragma unroll
                for (int j = 0; j < 4; j++)
                    acc[i][j] = __builtin_amdgcn_mfma_f32_16x16x32_bf16(bF[ks][j], aF[ks][i], acc[i][j], 0, 0, 0);
        __builtin_amdgcn_s_setprio(0);

        // counted wait: only step s+1's loads (issued one full step ago)
        if (s + 2 < TOT)      { VMW6(); __builtin_amdgcn_s_barrier(); }
        else if (s + 1 < TOT) { VMW0(); __builtin_amdgcn_s_barrier(); }

        if ((s + 1) % NT == 0) {             // tile finished -> epilogue
            EPI((s + 1) / NT - 1);
#pragma unroll
            for (int i = 0; i < 2; i++)
#pragma unroll
                for (int j = 0; j < 4; j++) acc[i][j] = (f32x4){0.f, 0.f, 0.f, 0.f};
        }
    }
}

// ---------------------------------------------------------------------------
// MFMA flash attention v2: double-buffered K/V staging (1 barrier/iter,
// prefetch issued post-barrier, consumed next iter), cvt_pk P-pack, softmax
// denominator via MFMA with ones-B (row-sum lands at q=quad*4+r per reg,
// matching oa — no epilogue shuffles), setprio around PV cluster.
// Q,K bf16 [bh][1024][32] (Q pre-scaled by rsqrt(32)*log2e); V bf16 transposed
// [bh][32][1024]. grid (128 bh, 8 q-tiles of 128), 256 thr = 4 waves x 32 q.
// ---------------------------------------------------------------------------
__global__ __launch_bounds__(256, 4) void attn_mfma(const ushort_t* __restrict__ Qb,
                                                    const ushort_t* __restrict__ Kb,
                                                    const ushort_t* __restrict__ Vtg,
                                                    ushort_t* __restrict__ o) {
    int bh = blockIdx.x;
    int b = bh >> 3, h = bh & 7;
    int q0 = blockIdx.y * 128;
    int tid = threadIdx.x;
    int wave = tid >> 6, lane = tid & 63;
    int l15 = lane & 15, quad = lane >> 4;

    __shared__ __align__(16) ushort_t Ks[2][64][40];     // [buf][key][d]
    __shared__ __align__(16) ushort_t Vs[2][32][88];     // [buf][d][key]
    __shared__ __align__(16) ushort_t Ps[4][32][72];     // per wave [q][key]

    const size_t hb = (size_t)bh * 32768;

    bf16x8 qfrag[2];
#pragma unroll
    for (int g = 0; g < 2; g++)
        qfrag[g] = *(const bf16x8*)(Qb + hb + (size_t)(q0 + wave * 32 + g * 16 + l15) * 32 + quad * 8);

    f32x4 oa[2][2];
#pragma unroll
    for (int g = 0; g < 2; g++)
#pragma unroll
        for (int t = 0; t < 2; t++) oa[g][t] = (f32x4){0.f, 0.f, 0.f, 0.f};
    f32x4 ls[2];
    ls[0] = (f32x4){0.f, 0.f, 0.f, 0.f};
    ls[1] = (f32x4){0.f, 0.f, 0.f, 0.f};

    bf16x8 ones;
#pragma unroll
    for (int i = 0; i < 8; i++) ones[i] = (short)0x3F80;   // bf16 1.0

    int krow = tid >> 2, kch = tid & 3;
    int vrow = tid >> 3, vch = tid & 7;
    const ushort_t* kgp = Kb + hb + (size_t)krow * 32 + kch * 8;
    const ushort_t* vgp = Vtg + hb + (size_t)vrow * 1024 + vch * 8;

    // prefetch tile 0 into registers
    bf16x8 kreg = *(const bf16x8*)kgp;
    bf16x8 vreg = *(const bf16x8*)vgp;

#pragma unroll 2
    for (int kt = 0; kt < 16; kt++) {
        const int cur = kt & 1;
        // write staged tile (consumes previous prefetch), then single barrier
        *(bf16x8*)&Ks[cur][krow][kch * 8] = kreg;
        *(bf16x8*)&Vs[cur][vrow][vch * 8] = vreg;
        __syncthreads();
        // issue next tile's loads now; latency hides under this iter's compute
        if (kt < 15) {
            kreg = *(const bf16x8*)(kgp + (kt + 1) * 2048);
            vreg = *(const bf16x8*)(vgp + (kt + 1) * 64);
        }

        bf16x8 kf[4];
#pragma unroll
        for (int kg = 0; kg < 4; kg++)
            kf[kg] = *(const bf16x8*)&Ks[cur][kg * 16 + l15][quad * 8];

        const f32x4 z = {0.f, 0.f, 0.f, 0.f};
#pragma unroll
        for (int g = 0; g < 2; g++) {
#pragma unroll
            for (int kg = 0; kg < 4; kg++) {
                f32x4 st = __builtin_amdgcn_mfma_f32_16x16x32_bf16(kf[kg], qfrag[g], z, 0, 0, 0);
                float e0 = __builtin_amdgcn_exp2f(st[0]);
                float e1 = __builtin_amdgcn_exp2f(st[1]);
                float e2 = __builtin_amdgcn_exp2f(st[2]);
                float e3 = __builtin_amdgcn_exp2f(st[3]);
                uint2 pk;
                pk.x = cvtpk_bf16(e0, e1);
                pk.y = cvtpk_bf16(e2, e3);
                *(uint2*)&Ps[wave][g * 16 + l15][kg * 16 + quad * 4] = pk;
            }
        }

        __builtin_amdgcn_s_setprio(1);
#pragma unroll
        for (int c = 0; c < 2; c++) {
            bf16x8 vb0 = *(const bf16x8*)&Vs[cur][l15][c * 32 + quad * 8];
            bf16x8 vb1 = *(const bf16x8*)&Vs[cur][16 + l15][c * 32 + quad * 8];
#pragma unroll
            for (int g = 0; g < 2; g++) {
                bf16x8 pa = *(const bf16x8*)&Ps[wave][g * 16 + l15][c * 32 + quad * 8];
                oa[g][0] = __builtin_amdgcn_mfma_f32_16x16x32_bf16(pa, vb0, oa[g][0], 0, 0, 0);
                oa[g][1] = __builtin_amdgcn_mfma_f32_16x16x32_bf16(pa, vb1, oa[g][1], 0, 0, 0);
                ls[g]    = __builtin_amdgcn_mfma_f32_16x16x32_bf16(pa, ones, ls[g], 0, 0, 0);
            }
        }
        __builtin_amdgcn_s_setprio(0);
    }

    // ls[g][r] = full row-sum of exp for q = g*16 + quad*4 + r (same mapping
    // as oa's q per reg) -> no cross-lane reduction needed.
#pragma unroll
    for (int g = 0; g < 2; g++) {
#pragma unroll
        for (int r = 0; r < 4; r++) {
            float inv = 1.f / ls[g][r];
            int q = q0 + wave * 32 + g * 16 + quad * 4 + r;
            ushort_t* orow = o + ((size_t)(b * 1024 + q)) * 256 + h * 32;
            orow[l15] = (ushort_t)f2bf(oa[g][0][r] * inv);
            orow[l15 + 16] = (ushort_t)f2bf(oa[g][1][r] * inv);
        }
    }
}

// ---------------------------------------------------------------------------
// Deformable gather -> bf16. One block per token, thread = (h=tid>>5, d=tid&31).
// ---------------------------------------------------------------------------
__global__ __launch_bounds__(256) void deform_kernel(const float* __restrict__ ref,
                                                     const float* __restrict__ off,
                                                     const float* __restrict__ awl,
                                                     const float* __restrict__ v,
                                                     ushort_t* __restrict__ out) {
    int t = blockIdx.x;
    int b = t >> 10;
    int tid = threadIdx.x;
    int h = tid >> 5, d = tid & 31;

    float rx = ref[(size_t)t * 2 + 0];
    float ry = ref[(size_t)t * 2 + 1];
    const float* offr = off + (size_t)t * 64 + h * 8;
    const float* awr = awl + (size_t)t * 32 + h * 4;

    float L0 = awr[0], L1 = awr[1], L2 = awr[2], L3 = awr[3];
    float mm = fmaxf(fmaxf(L0, L1), fmaxf(L2, L3));
    float e0 = __expf(L0 - mm), e1 = __expf(L1 - mm), e2 = __expf(L2 - mm), e3 = __expf(L3 - mm);
    float inv = 1.f / (e0 + e1 + e2 + e3);
    float aw[4] = {e0 * inv, e1 * inv, e2 * inv, e3 * inv};

    const float* vb = v + (size_t)b * Nq * Cq + h * 32 + d;

    float s = 0.f;
#pragma unroll
    for (int p = 0; p < 4; p++) {
        float gx = rx * 32.f + offr[p * 2 + 0] - 0.5f;
        float gy = ry * 32.f + offr[p * 2 + 1] - 0.5f;
        float x0f = floorf(gx), y0f = floorf(gy);
        float lx = gx - x0f, ly = gy - y0f;
        int x0 = (int)x0f, y0 = (int)y0f;
        auto g = [&](int xi, int yi) -> float {
            if (xi < 0 || xi > 31 || yi < 0 || yi > 31) return 0.f;
            return vb[(size_t)(yi * 32 + xi) * Cq];
        };
        float sp = g(x0, y0) * (1.f - lx) * (1.f - ly)
                 + g(x0 + 1, y0) * lx * (1.f - ly)
                 + g(x0, y0 + 1) * (1.f - lx) * ly
                 + g(x0 + 1, y0 + 1) * lx * ly;
        s += aw[p] * sp;
    }
    out[(size_t)t * Cq + h * 32 + d] = (ushort_t)f2bf(s);
}

// ---------------------------------------------------------------------------
// Launch
// ---------------------------------------------------------------------------
extern "C" void kernel_launch(void* const* d_in, const int* in_sizes, int n_in,
                              void* d_out, int out_size, void* d_ws, size_t ws_size,
                              hipStream_t stream) {
    const size_t S = (size_t)BNq * Cq;  // 4,194,304
    float* ws = (float*)d_ws;
    float* X = ws;                                  // [0, S) residual fp32
    ushort_t* Ybf = (ushort_t*)(ws + S);            // [S, 1.5S)
    ushort_t* Wbf = (ushort_t*)(ws + S + S / 2);    // [1.5S, 2S)

    ushort_t* Wqkv   = Wbf;
    ushort_t* Wproj  = Wbf + 196608;
    ushort_t* Woff   = Wbf + 262144;   // off(64 rows) + aw(32 rows) contiguous
    ushort_t* Waw    = Wbf + 278528;
    ushort_t* Wvproj = Wbf + 286720;
    ushort_t* Woproj = Wbf + 352256;
    ushort_t* Wfc1   = Wbf + 417792;
    ushort_t* Wfc2   = Wbf + 679936;

    ushort_t* QKVbf = (ushort_t*)(ws + 2 * S);              // Q,K,V^T: [2S, 3.5S)
    ushort_t* O1bf  = (ushort_t*)(ws + 2 * S + 3 * S / 2);  // [3.5S, 4S)
    float* Vb   = ws + 2 * S + S / 2;                       // [2.5S, 3.5S)
    float* OffB = ws + 2 * S + 3 * S / 2;                   // [3.5S, 3.75S)
    float* AwB  = OffB + (size_t)BNq * 64;                  // [3.75S, 3.875S) (contiguous after OffB)
    ushort_t* Sbbf = (ushort_t*)(AwB + (size_t)BNq * 32);   // [3.875S, 4.375S)
    ushort_t* Hbbf = (ushort_t*)(ws + 2 * S);               // [2S, 4S)
    ushort_t* Valbf = (ushort_t*)(ws + 9 * S / 2);          // [4.5S, 5S)

    auto fp = [&](int i) { return (const float*)d_in[i]; };
    const float* x_in = fp(0);

    // ---- all fp32->bf16 casts in one dispatch ----
    CastArgs ca;
    ca.s[0] = {fp(9),  Wqkv,   192, 196608};
    ca.s[1] = {fp(10), Wproj,  64,  65536};
    ca.s[2] = {fp(12), Woff,   16,  16384};
    ca.s[3] = {fp(14), Waw,    8,   8192};
    ca.s[4] = {fp(16), Wvproj, 64,  65536};
    ca.s[5] = {fp(18), Woproj, 64,  65536};
    ca.s[6] = {fp(20), Wfc1,   256, 262144};
    ca.s[7] = {fp(22), Wfc2,   256, 262144};
    ca.s[8] = {fp(2),  Valbf,  4096, (int)S};
    castm<<<5016, 256, 0, stream>>>(ca);

    // ---- stage 1: self-attention ----
    ln_kernel<<<BNq / 4, 256, 0, stream>>>(x_in, fp(3), fp(4), Ybf);
    mgemm<1, false, false, 256, 2><<<dim3(64, 12), 256, 0, stream>>>(
        Ybf, Wqkv, nullptr, nullptr, QKVbf, BNq, 768);
    attn_mfma<<<dim3(128, 8), 256, 0, stream>>>(
        QKVbf, QKVbf + S, QKVbf + 2 * S, O1bf);
    mgemm<0, false, true, 256, 1><<<dim3(128, 4), 256, 0, stream>>>(
        O1bf, Wproj, fp(11), x_in, X, BNq, 256);

    // ---- stage 2: deformable attention ----
    ln_kernel<<<BNq / 4, 256, 0, stream>>>(X, fp(5), fp(6), Ybf);
    mgemm<0, false, false, 256, 1><<<dim3(128, 4), 256, 0, stream>>>(
        Valbf, Wvproj, fp(17), nullptr, Vb, BNq, 256);
    mgemm<3, false, false, 256, 1><<<dim3(128, 2), 256, 0, stream>>>(
        Ybf, Woff, fp(13), fp(15), OffB, BNq, 96);
    deform_kernel<<<BNq, 256, 0, stream>>>(fp(1), OffB, AwB, Vb, Sbbf);
    mgemm<0, false, true, 256, 1><<<dim3(128, 4), 256, 0, stream>>>(
        Sbbf, Woproj, fp(19), X, X, BNq, 256);

    // ---- stage 3: MLP ----
    ln_kernel<<<BNq / 4, 256, 0, stream>>>(X, fp(7), fp(8), Ybf);
    mgemm<2, true, false, 256, 4><<<dim3(32, 16), 256, 0, stream>>>(
        Ybf, Wfc1, fp(21), nullptr, Hbbf, BNq, 1024);
    mgemm<0, false, true, 1024, 1><<<dim3(128, 4), 256, 0, stream>>>(
        Hbbf, Wfc2, fp(23), X, d_out, BNq, 256);
}

// Round 9
// 327.585 us; speedup vs baseline: 1.0412x; 1.0412x over previous
//
#include <hip/hip_runtime.h>
#include <hip/hip_bf16.h>

// Problem constants
#define Bq   16
#define Nq   1024
#define Cq   256
#define NHq  8
#define DHq  32
#define HIDq 1024
#define BNq  (Bq * Nq)   // 16384 tokens

typedef float f32x4 __attribute__((ext_vector_type(4)));
typedef short bf16x8 __attribute__((ext_vector_type(8)));
typedef unsigned short ushort_t;

__device__ __forceinline__ unsigned int f2bf(float f) {   // RNE
    unsigned int u = __builtin_bit_cast(unsigned int, f);
    u = (u + 0x7fffu + ((u >> 16) & 1u)) >> 16;
    return u & 0xffffu;
}
// pack two floats -> two bf16 (round-half-up) in one dword via v_perm
__device__ __forceinline__ unsigned int packbf2(float a, float b) {
    unsigned int ua = __builtin_bit_cast(unsigned int, a) + 0x8000u;
    unsigned int ub = __builtin_bit_cast(unsigned int, b) + 0x8000u;
    return __builtin_amdgcn_perm(ub, ua, 0x07060302);
}
// single-instruction packed f32x2 -> bf16x2 (RNE); lo -> low half
__device__ __forceinline__ unsigned int cvtpk_bf16(float lo, float hi) {
    unsigned int r;
    asm("v_cvt_pk_bf16_f32 %0, %1, %2" : "=v"(r) : "v"(lo), "v"(hi));
    return r;
}
// branch-free tanh-approx GELU
__device__ __forceinline__ float gelu_t(float x) {
    float y = x * (0.7978845608028654f + 0.035677408136300125f * x * x);
    float e = __builtin_amdgcn_exp2f(y * 2.8853900817779268f);
    return x - x / (1.f + e);
}

typedef __attribute__((address_space(1))) const unsigned int* gas_u32;
typedef __attribute__((address_space(3))) unsigned int* las_u32;
__device__ __forceinline__ void gload16(const void* g, void* l) {
    __builtin_amdgcn_global_load_lds((gas_u32)g, (las_u32)l, 16, 0, 0);
}

// ---------------------------------------------------------------------------
// Fused fp32 -> bf16 casts: 9 segments in one dispatch.
// ---------------------------------------------------------------------------
struct CastSeg { const float* src; ushort_t* dst; int nblk; int n; };
struct CastArgs { CastSeg s[9]; };

__global__ __launch_bounds__(256) void castm(CastArgs a) {
    int bid = blockIdx.x;
    int seg = 0, acc = 0;
    for (seg = 0; seg < 9; seg++) {
        if (bid < acc + a.s[seg].nblk) break;
        acc += a.s[seg].nblk;
    }
    const CastSeg sg = a.s[seg];
    int i = (bid - acc) * 1024 + threadIdx.x * 4;
    if (i < sg.n) {
        float4 v = *(const float4*)(sg.src + i);
        uint2 u;
        u.x = packbf2(v.x, v.y);
        u.y = packbf2(v.z, v.w);
        *(uint2*)(sg.dst + i) = u;
    }
}

// ---------------------------------------------------------------------------
// LayerNorm over C=256 -> bf16. One wave per token, 4 tokens per block.
// ---------------------------------------------------------------------------
__global__ __launch_bounds__(256) void ln_kernel(const float* __restrict__ X,
                                                 const float* __restrict__ w,
                                                 const float* __restrict__ b,
                                                 ushort_t* __restrict__ Y) {
    int wave = threadIdx.x >> 6, lane = threadIdx.x & 63;
    int t = blockIdx.x * 4 + wave;
    float4 v = *(const float4*)(X + (size_t)t * Cq + lane * 4);
    float s = v.x + v.y + v.z + v.w;
#pragma unroll
    for (int d = 1; d < 64; d <<= 1) s += __shfl_xor(s, d);
    float mean = s * (1.f / 256.f);
    float4 dv = {v.x - mean, v.y - mean, v.z - mean, v.w - mean};
    float q = dv.x * dv.x + dv.y * dv.y + dv.z * dv.z + dv.w * dv.w;
#pragma unroll
    for (int d = 1; d < 64; d <<= 1) q += __shfl_xor(q, d);
    float rs = rsqrtf(q * (1.f / 256.f) + 1e-5f);
    float4 wv = *(const float4*)(w + lane * 4);
    float4 bv = *(const float4*)(b + lane * 4);
    uint2 u;
    u.x = packbf2(dv.x * rs * wv.x + bv.x, dv.y * rs * wv.y + bv.y);
    u.y = packbf2(dv.z * rs * wv.z + bv.z, dv.w * rs * wv.w + bv.w);
    *(uint2*)(Y + (size_t)t * Cq + lane * 4) = u;
}

// ---------------------------------------------------------------------------
// MFMA GEMM with counted-vmcnt double-buffered pipeline (R4 structure —
// measured best for the small projection GEMMs).
// BM=128, BN=64, BK=64; 4 waves, wave w owns rows [w*32, w*32+32).
// LDS: A 2x16KB, B 2x8KB = 48KB. Fragment-ordered chunks: chunk c (0..7)
// holds k=(c&3)*8+(c>>2)*32; wave w stages chunks {w, w+4}.
// Per iter t (cur=t&1): ds_read 12 frags(cur) -> lgkm(0) -> barrier ->
// STAGE(cur, t+2) -> 16 MFMA -> vmcnt(6) [waits only tile t+1] -> barrier.
// MFMA operands swapped (C^T): thread holds 4 consecutive n-values.
// OMODE 0: fp32 out (+bias/residual); OMODE 1: qkv -> bf16 head-major
//          (Q scaled by rsqrt(32)*log2e, V transposed [bh][32][1024]);
// OMODE 2: bf16 out; OMODE 3: fused off/aw (ng<64 -> OffB w/ bias, else AwB
//          w/ R-as-bias; AwB = OutP + BN*64).
// ---------------------------------------------------------------------------
template <int OMODE, bool GELU_, bool RESID, int KT>
__global__ __launch_bounds__(256) void mgemm(const ushort_t* __restrict__ A,
                                             const ushort_t* __restrict__ W,
                                             const float* __restrict__ bias,
                                             const float* __restrict__ R,
                                             void* __restrict__ OutP,
                                             int M, int Nn) {
    __shared__ __align__(16) ushort_t Al[2][8192];
    __shared__ __align__(16) ushort_t Bl[2][4096];
    int m0 = blockIdx.x * 128, n0 = blockIdx.y * 64;
    int tid = threadIdx.x;
    int w = tid >> 6, lane = tid & 63;
    int l15 = lane & 15, quad = lane >> 4;

    f32x4 acc[2][4];
#pragma unroll
    for (int i = 0; i < 2; i++)
#pragma unroll
        for (int j = 0; j < 4; j++) acc[i][j] = (f32x4){0.f, 0.f, 0.f, 0.f};

    const ushort_t* gA0 = A + (size_t)(m0 + lane) * KT + w * 8;
    const ushort_t* gA1 = gA0 + (size_t)64 * KT;
    const ushort_t* gB0 = W + (size_t)(n0 + lane) * KT + w * 8;

    auto STAGE = [&](int buf, int t) {
        const int k0 = t * 64;
        gload16(gA0 + k0,      &Al[buf][w * 1024]);
        gload16(gA1 + k0,      &Al[buf][w * 1024 + 512]);
        gload16(gA0 + k0 + 32, &Al[buf][(w + 4) * 1024]);
        gload16(gA1 + k0 + 32, &Al[buf][(w + 4) * 1024 + 512]);
        gload16(gB0 + k0,      &Bl[buf][w * 512]);
        gload16(gB0 + k0 + 32, &Bl[buf][(w + 4) * 512]);
    };

    constexpr int NT = KT / 64;
    STAGE(0, 0);
    STAGE(1, 1);
    asm volatile("s_waitcnt vmcnt(6)" ::: "memory");   // tile 0 landed
    __builtin_amdgcn_s_barrier();

#pragma unroll
    for (int t = 0; t < NT; t++) {
        const int cur = t & 1;
        bf16x8 aF[2][2], bF[2][4];
#pragma unroll
        for (int ks = 0; ks < 2; ks++) {
#pragma unroll
            for (int i = 0; i < 2; i++)
                aF[ks][i] = *(const bf16x8*)&Al[cur][(ks * 4 + quad) * 1024 + (w * 32 + i * 16 + l15) * 8];
#pragma unroll
            for (int j = 0; j < 4; j++)
                bF[ks][j] = *(const bf16x8*)&Bl[cur][(ks * 4 + quad) * 512 + (j * 16 + l15) * 8];
        }
        asm volatile("s_waitcnt lgkmcnt(0)" ::: "memory");
        __builtin_amdgcn_sched_barrier(0);
        __builtin_amdgcn_s_barrier();        // all waves done reading cur
        if (t + 2 < NT) STAGE(cur, t + 2);

        __builtin_amdgcn_s_setprio(1);
#pragma unroll
        for (int ks = 0; ks < 2; ks++)
#pragma unroll
            for (int i = 0; i < 2; i++)
#pragma unroll
                for (int j = 0; j < 4; j++)
                    acc[i][j] = __builtin_amdgcn_mfma_f32_16x16x32_bf16(bF[ks][j], aF[ks][i], acc[i][j], 0, 0, 0);
        __builtin_amdgcn_s_setprio(0);

        if (t + 2 < NT) {
            asm volatile("s_waitcnt vmcnt(6)" ::: "memory");
        } else if (t + 1 < NT) {
            asm volatile("s_waitcnt vmcnt(0)" ::: "memory");
        }
        if (t + 1 < NT) __builtin_amdgcn_s_barrier();
    }

#pragma unroll
    for (int i = 0; i < 2; i++) {
        int mg = m0 + w * 32 + i * 16 + l15;
#pragma unroll
        for (int j = 0; j < 4; j++) {
            int ng = n0 + j * 16 + quad * 4;
            f32x4 rv = acc[i][j];
            if constexpr (OMODE == 1) {
                int which = ng >> 8;
                int h = (ng >> 5) & 7;
                int d = ng & 31;
                int bb = mg >> 10, nn = mg & 1023;
                ushort_t* qb = (ushort_t*)OutP;
                if (which == 2) {          // V transposed: [bh][d][n]
                    size_t dst = 2 * (size_t)BNq * Cq +
                                 ((size_t)(bb * 8 + h) * 32 + d) * 1024 + nn;
#pragma unroll
                    for (int r = 0; r < 4; r++)
                        qb[dst + (size_t)r * 1024] = (ushort_t)f2bf(rv[r]);
                } else {
                    if (which == 0) {
                        const float sc = 0.17677669529663687f * 1.4426950408889634f;
                        rv[0] *= sc; rv[1] *= sc; rv[2] *= sc; rv[3] *= sc;
                    }
                    size_t dst = (size_t)which * ((size_t)BNq * Cq) +
                                 ((size_t)(bb * 8 + h) * 1024 + nn) * 32 + d;
                    uint2 pk;
                    pk.x = packbf2(rv[0], rv[1]);
                    pk.y = packbf2(rv[2], rv[3]);
                    *(uint2*)(qb + dst) = pk;
                }
            } else if constexpr (OMODE == 3) {
                if (ng >= 96) continue;
                if (ng < 64) {
                    float4 bv = *(const float4*)(bias + ng);
                    rv[0] += bv.x; rv[1] += bv.y; rv[2] += bv.z; rv[3] += bv.w;
                    *(float4*)((float*)OutP + (size_t)mg * 64 + ng) =
                        make_float4(rv[0], rv[1], rv[2], rv[3]);
                } else {
                    float4 bv = *(const float4*)(R + (ng - 64));
                    rv[0] += bv.x; rv[1] += bv.y; rv[2] += bv.z; rv[3] += bv.w;
                    *(float4*)((float*)OutP + (size_t)BNq * 64 + (size_t)mg * 32 + (ng - 64)) =
                        make_float4(rv[0], rv[1], rv[2], rv[3]);
                }
            } else {
                if (bias) {
                    float4 bv = *(const float4*)(bias + ng);
                    rv[0] += bv.x; rv[1] += bv.y; rv[2] += bv.z; rv[3] += bv.w;
                }
                if (GELU_) {
#pragma unroll
                    for (int r = 0; r < 4; r++) rv[r] = gelu_t(rv[r]);
                }
                if constexpr (OMODE == 2) {
                    uint2 pk;
                    pk.x = packbf2(rv[0], rv[1]);
                    pk.y = packbf2(rv[2], rv[3]);
                    *(uint2*)((ushort_t*)OutP + (size_t)mg * Nn + ng) = pk;
                } else {
                    if (RESID) {
                        float4 rr = *(const float4*)(R + (size_t)mg * Nn + ng);
                        rv[0] += rr.x; rv[1] += rr.y; rv[2] += rr.z; rv[3] += rr.w;
                    }
                    *(float4*)((float*)OutP + (size_t)mg * Nn + ng) =
                        make_float4(rv[0], rv[1], rv[2], rv[3]);
                }
            }
        }
    }
}

// ---------------------------------------------------------------------------
// Fused MLP: out = X + gelu(Y @ W1^T + b1) @ W2^T + b2, H never leaves LDS.
// Block = 64 m-rows (grid 256 = 1/CU), 4 waves. 16 hid-chunks of 64.
// A (Y rows) in REGISTERS (wave w holds rows [w*16,+16) as 8x bf16x8);
// b1 staged to LDS once (no VMEM loads in the loop -> clean vmcnt ledger).
// LDS 108KB: W1 2x32KB (dbuf) + W2 32KB (single) + H 8KB + b1 4KB.
// Per chunk ch (cur=ch&1), counted-vmcnt ledger (8 loads per SW group):
//   GEMM1(W1l[cur],aF) -> bias+gelu -> H ds_write -> lgkm(0) -> barrier
//   -> SW1(cur,ch+2) -> vmcnt(8) [drains SW2(ch), issued a full chunk ago;
//   queue: SW1(ch+1),SW2(ch),SW1(ch+2) -> leave 8] -> barrier -> GEMM2
//   (Hl x W2l -> acc2 persists) -> lgkm(0) -> barrier -> SW2(ch+1).
// Tail: vmcnt(0) when no SW1 issued. Epilogue adds b2 + X residual.
// Layouts (fragment-ordered 8-k chunks, chunk c holds k=(c&3)*8+(c>>2)*32):
//   W1l: [kc 0..31][row h 0..63][8]   addr kc*512+row*8
//   W2l: [kc2 0..7][row n 0..255][8]  addr kc2*2048+row*8
//   Hl : [kh 0..7][row m 0..63][8]    addr kh*512+row*8
// ---------------------------------------------------------------------------
__global__ __launch_bounds__(256) void mlp_fused(const ushort_t* __restrict__ Y,
                                                 const ushort_t* __restrict__ W1,
                                                 const float* __restrict__ b1,
                                                 const ushort_t* __restrict__ W2,
                                                 const float* __restrict__ b2,
                                                 const float* __restrict__ Xr,
                                                 float* __restrict__ out) {
    __shared__ __align__(16) ushort_t W1l[2][16384];   // 64 KB
    __shared__ __align__(16) ushort_t W2l[16384];      // 32 KB
    __shared__ __align__(16) ushort_t Hl[4096];        // 8 KB
    __shared__ __align__(16) float b1l[1024];          // 4 KB
    int m0 = blockIdx.x * 64;
    int tid = threadIdx.x;
    int w = tid >> 6, lane = tid & 63;
    int l15 = lane & 15, quad = lane >> 4;

    // A rows in registers: row = m0 + w*16 + l15, k = ks*32 + quad*8
    bf16x8 aF[8];
    {
        const ushort_t* ga = Y + (size_t)(m0 + w * 16 + l15) * 256 + quad * 8;
#pragma unroll
        for (int ks = 0; ks < 8; ks++) aF[ks] = *(const bf16x8*)(ga + ks * 32);
    }

    // stage W1 chunk ch (64 h-rows x 256 k): wave w stages kc = w + 4j
    auto SW1 = [&](int buf, int ch) {
        const ushort_t* g = W1 + (size_t)(ch * 64 + lane) * 256 + w * 8;
#pragma unroll
        for (int j = 0; j < 8; j++)
            gload16(g + j * 32, &W1l[buf][(w + 4 * j) * 512]);
    };
    // stage W2 chunk ch (256 n-rows x 64 hid): wave w stages kc2 = {w, w+4}
    auto SW2 = [&](int ch) {
#pragma unroll
        for (int jj = 0; jj < 8; jj++) {
            const int kc2 = (jj & 1) * 4 + w;
            const int rj = jj >> 1;              // n-row group of 64
            const ushort_t* g = W2 + (size_t)(rj * 64 + lane) * 1024 + ch * 64 +
                                (kc2 & 3) * 8 + (kc2 >> 2) * 32;
            gload16(g, &W2l[kc2 * 2048 + rj * 512]);
        }
    };

    f32x4 acc2[4][4];
#pragma unroll
    for (int i = 0; i < 4; i++)
#pragma unroll
        for (int j = 0; j < 4; j++) acc2[i][j] = (f32x4){0.f, 0.f, 0.f, 0.f};

    // prologue. queue: aF(8), SW1(0)(8), SW2(0)(8), b1(1), SW1(1)(8) = 33
    SW1(0, 0);
    SW2(0);
    gload16(b1 + w * 256 + lane * 4, &b1l[w * 256]);   // bias -> LDS
    SW1(1, 1);
    asm volatile("s_waitcnt vmcnt(8)" ::: "memory");   // all but SW1(1) landed
    __builtin_amdgcn_s_barrier();

    for (int ch = 0; ch < 16; ch++) {
        const int cur = ch & 1;

        // ---- GEMM1: H(64x64) = A(64x256) @ W1[ch]^T ----
        f32x4 acc1[4];
#pragma unroll
        for (int j = 0; j < 4; j++) acc1[j] = (f32x4){0.f, 0.f, 0.f, 0.f};
#pragma unroll
        for (int ks = 0; ks < 8; ks++) {
            bf16x8 bF[4];
#pragma unroll
            for (int j = 0; j < 4; j++)
                bF[j] = *(const bf16x8*)&W1l[cur][(ks * 4 + quad) * 512 + (j * 16 + l15) * 8];
#pragma unroll
            for (int j = 0; j < 4; j++)
                acc1[j] = __builtin_amdgcn_mfma_f32_16x16x32_bf16(bF[j], aF[ks], acc1[j], 0, 0, 0);
        }
        // ---- bias + gelu -> H LDS (GEMM2-fragment order) ----
#pragma unroll
        for (int j = 0; j < 4; j++) {
            float4 b1v = *(const float4*)&b1l[ch * 64 + j * 16 + quad * 4];
            f32x4 rv = acc1[j];
            rv[0] = gelu_t(rv[0] + b1v.x);
            rv[1] = gelu_t(rv[1] + b1v.y);
            rv[2] = gelu_t(rv[2] + b1v.z);
            rv[3] = gelu_t(rv[3] + b1v.w);
            int h = j * 16 + quad * 4;
            uint2 pk;
            pk.x = cvtpk_bf16(rv[0], rv[1]);
            pk.y = cvtpk_bf16(rv[2], rv[3]);
            *(uint2*)&Hl[((h >> 3) * 64 + (w * 16 + l15)) * 8 + (h & 7)] = pk;
        }
        asm volatile("s_waitcnt lgkmcnt(0)" ::: "memory");  // H writes committed
        __builtin_amdgcn_s_barrier();          // H visible; W1l[cur] free
        if (ch + 2 < 16) {
            SW1(cur, ch + 2);
            asm volatile("s_waitcnt vmcnt(8)" ::: "memory"); // SW2(ch) landed
        } else {
            asm volatile("s_waitcnt vmcnt(0)" ::: "memory");
        }
        __builtin_amdgcn_s_barrier();          // W2[ch] visible to all waves

        // ---- GEMM2: acc2 += H(64x64) @ W2[ch]^T (wave w owns n [w*64,+64)) ----
        __builtin_amdgcn_s_setprio(1);
#pragma unroll
        for (int ks2 = 0; ks2 < 2; ks2++) {
            bf16x8 a2[4], b2f[4];
#pragma unroll
            for (int i = 0; i < 4; i++)
                a2[i] = *(const bf16x8*)&Hl[(ks2 * 4 + quad) * 512 + (i * 16 + l15) * 8];
#pragma unroll
            for (int j = 0; j < 4; j++)
                b2f[j] = *(const bf16x8*)&W2l[(ks2 * 4 + quad) * 2048 + (w * 64 + j * 16 + l15) * 8];
#pragma unroll
            for (int i = 0; i < 4; i++)
#pragma unroll
                for (int j = 0; j < 4; j++)
                    acc2[i][j] = __builtin_amdgcn_mfma_f32_16x16x32_bf16(b2f[j], a2[i], acc2[i][j], 0, 0, 0);
        }
        __builtin_amdgcn_s_setprio(0);
        asm volatile("s_waitcnt lgkmcnt(0)" ::: "memory");  // LDS reads retired
        __builtin_amdgcn_s_barrier();          // W2l + Hl free for overwrite
        if (ch + 1 < 16) SW2(ch + 1);
    }

    // ---- epilogue: out = acc2 + b2 + X ----
#pragma unroll
    for (int i = 0; i < 4; i++) {
        int mg = m0 + i * 16 + l15;
#pragma unroll
        for (int j = 0; j < 4; j++) {
            int ng = w * 64 + j * 16 + quad * 4;
            f32x4 rv = acc2[i][j];
            float4 bv = *(const float4*)(b2 + ng);
            float4 rr = *(const float4*)(Xr + (size_t)mg * 256 + ng);
            rv[0] += bv.x + rr.x; rv[1] += bv.y + rr.y;
            rv[2] += bv.z + rr.z; rv[3] += bv.w + rr.w;
            *(float4*)(out + (size_t)mg * 256 + ng) =
                make_float4(rv[0], rv[1], rv[2], rv[3]);
        }
    }
}

// ---------------------------------------------------------------------------
// MFMA flash attention v2 (unchanged from R4).
// ---------------------------------------------------------------------------
__global__ __launch_bounds__(256, 4) void attn_mfma(const ushort_t* __restrict__ Qb,
                                                    const ushort_t* __restrict__ Kb,
                                                    const ushort_t* __restrict__ Vtg,
                                                    ushort_t* __restrict__ o) {
    int bh = blockIdx.x;
    int b = bh >> 3, h = bh & 7;
    int q0 = blockIdx.y * 128;
    int tid = threadIdx.x;
    int wave = tid >> 6, lane = tid & 63;
    int l15 = lane & 15, quad = lane >> 4;

    __shared__ __align__(16) ushort_t Ks[2][64][40];     // [buf][key][d]
    __shared__ __align__(16) ushort_t Vs[2][32][88];     // [buf][d][key]
    __shared__ __align__(16) ushort_t Ps[4][32][72];     // per wave [q][key]

    const size_t hb = (size_t)bh * 32768;

    bf16x8 qfrag[2];
#pragma unroll
    for (int g = 0; g < 2; g++)
        qfrag[g] = *(const bf16x8*)(Qb + hb + (size_t)(q0 + wave * 32 + g * 16 + l15) * 32 + quad * 8);

    f32x4 oa[2][2];
#pragma unroll
    for (int g = 0; g < 2; g++)
#pragma unroll
        for (int t = 0; t < 2; t++) oa[g][t] = (f32x4){0.f, 0.f, 0.f, 0.f};
    f32x4 ls[2];
    ls[0] = (f32x4){0.f, 0.f, 0.f, 0.f};
    ls[1] = (f32x4){0.f, 0.f, 0.f, 0.f};

    bf16x8 ones;
#pragma unroll
    for (int i = 0; i < 8; i++) ones[i] = (short)0x3F80;   // bf16 1.0

    int krow = tid >> 2, kch = tid & 3;
    int vrow = tid >> 3, vch = tid & 7;
    const ushort_t* kgp = Kb + hb + (size_t)krow * 32 + kch * 8;
    const ushort_t* vgp = Vtg + hb + (size_t)vrow * 1024 + vch * 8;

    // prefetch tile 0 into registers
    bf16x8 kreg = *(const bf16x8*)kgp;
    bf16x8 vreg = *(const bf16x8*)vgp;

#pragma unroll 2
    for (int kt = 0; kt < 16; kt++) {
        const int cur = kt & 1;
        *(bf16x8*)&Ks[cur][krow][kch * 8] = kreg;
        *(bf16x8*)&Vs[cur][vrow][vch * 8] = vreg;
        __syncthreads();
        if (kt < 15) {
            kreg = *(const bf16x8*)(kgp + (kt + 1) * 2048);
            vreg = *(const bf16x8*)(vgp + (kt + 1) * 64);
        }

        bf16x8 kf[4];
#pragma unroll
        for (int kg = 0; kg < 4; kg++)
            kf[kg] = *(const bf16x8*)&Ks[cur][kg * 16 + l15][quad * 8];

        const f32x4 z = {0.f, 0.f, 0.f, 0.f};
#pragma unroll
        for (int g = 0; g < 2; g++) {
#pragma unroll
            for (int kg = 0; kg < 4; kg++) {
                f32x4 st = __builtin_amdgcn_mfma_f32_16x16x32_bf16(kf[kg], qfrag[g], z, 0, 0, 0);
                float e0 = __builtin_amdgcn_exp2f(st[0]);
                float e1 = __builtin_amdgcn_exp2f(st[1]);
                float e2 = __builtin_amdgcn_exp2f(st[2]);
                float e3 = __builtin_amdgcn_exp2f(st[3]);
                uint2 pk;
                pk.x = cvtpk_bf16(e0, e1);
                pk.y = cvtpk_bf16(e2, e3);
                *(uint2*)&Ps[wave][g * 16 + l15][kg * 16 + quad * 4] = pk;
            }
        }

        __builtin_amdgcn_s_setprio(1);
#pragma unroll
        for (int c = 0; c < 2; c++) {
            bf16x8 vb0 = *(const bf16x8*)&Vs[cur][l15][c * 32 + quad * 8];
            bf16x8 vb1 = *(const bf16x8*)&Vs[cur][16 + l15][c * 32 + quad * 8];
#pragma unroll
            for (int g = 0; g < 2; g++) {
                bf16x8 pa = *(const bf16x8*)&Ps[wave][g * 16 + l15][c * 32 + quad * 8];
                oa[g][0] = __builtin_amdgcn_mfma_f32_16x16x32_bf16(pa, vb0, oa[g][0], 0, 0, 0);
                oa[g][1] = __builtin_amdgcn_mfma_f32_16x16x32_bf16(pa, vb1, oa[g][1], 0, 0, 0);
                ls[g]    = __builtin_amdgcn_mfma_f32_16x16x32_bf16(pa, ones, ls[g], 0, 0, 0);
            }
        }
        __builtin_amdgcn_s_setprio(0);
    }

#pragma unroll
    for (int g = 0; g < 2; g++) {
#pragma unroll
        for (int r = 0; r < 4; r++) {
            float inv = 1.f / ls[g][r];
            int q = q0 + wave * 32 + g * 16 + quad * 4 + r;
            ushort_t* orow = o + ((size_t)(b * 1024 + q)) * 256 + h * 32;
            orow[l15] = (ushort_t)f2bf(oa[g][0][r] * inv);
            orow[l15 + 16] = (ushort_t)f2bf(oa[g][1][r] * inv);
        }
    }
}

// ---------------------------------------------------------------------------
// Deformable gather -> bf16. One block per token, thread = (h=tid>>5, d=tid&31).
// ---------------------------------------------------------------------------
__global__ __launch_bounds__(256) void deform_kernel(const float* __restrict__ ref,
                                                     const float* __restrict__ off,
                                                     const float* __restrict__ awl,
                                                     const float* __restrict__ v,
                                                     ushort_t* __restrict__ out) {
    int t = blockIdx.x;
    int b = t >> 10;
    int tid = threadIdx.x;
    int h = tid >> 5, d = tid & 31;

    float rx = ref[(size_t)t * 2 + 0];
    float ry = ref[(size_t)t * 2 + 1];
    const float* offr = off + (size_t)t * 64 + h * 8;
    const float* awr = awl + (size_t)t * 32 + h * 4;

    float L0 = awr[0], L1 = awr[1], L2 = awr[2], L3 = awr[3];
    float mm = fmaxf(fmaxf(L0, L1), fmaxf(L2, L3));
    float e0 = __expf(L0 - mm), e1 = __expf(L1 - mm), e2 = __expf(L2 - mm), e3 = __expf(L3 - mm);
    float inv = 1.f / (e0 + e1 + e2 + e3);
    float aw[4] = {e0 * inv, e1 * inv, e2 * inv, e3 * inv};

    const float* vb = v + (size_t)b * Nq * Cq + h * 32 + d;

    float s = 0.f;
#pragma unroll
    for (int p = 0; p < 4; p++) {
        float gx = rx * 32.f + offr[p * 2 + 0] - 0.5f;
        float gy = ry * 32.f + offr[p * 2 + 1] - 0.5f;
        float x0f = floorf(gx), y0f = floorf(gy);
        float lx = gx - x0f, ly = gy - y0f;
        int x0 = (int)x0f, y0 = (int)y0f;
        auto g = [&](int xi, int yi) -> float {
            if (xi < 0 || xi > 31 || yi < 0 || yi > 31) return 0.f;
            return vb[(size_t)(yi * 32 + xi) * Cq];
        };
        float sp = g(x0, y0) * (1.f - lx) * (1.f - ly)
                 + g(x0 + 1, y0) * lx * (1.f - ly)
                 + g(x0, y0 + 1) * (1.f - lx) * ly
                 + g(x0 + 1, y0 + 1) * lx * ly;
        s += aw[p] * sp;
    }
    out[(size_t)t * Cq + h * 32 + d] = (ushort_t)f2bf(s);
}

// ---------------------------------------------------------------------------
// Launch
// ---------------------------------------------------------------------------
extern "C" void kernel_launch(void* const* d_in, const int* in_sizes, int n_in,
                              void* d_out, int out_size, void* d_ws, size_t ws_size,
                              hipStream_t stream) {
    const size_t S = (size_t)BNq * Cq;  // 4,194,304
    float* ws = (float*)d_ws;
    float* X = ws;                                  // [0, S) residual fp32
    ushort_t* Ybf = (ushort_t*)(ws + S);            // [S, 1.5S)
    ushort_t* Wbf = (ushort_t*)(ws + S + S / 2);    // [1.5S, 2S)

    ushort_t* Wqkv   = Wbf;
    ushort_t* Wproj  = Wbf + 196608;
    ushort_t* Woff   = Wbf + 262144;   // off(64 rows) + aw(32 rows) contiguous
    ushort_t* Waw    = Wbf + 278528;
    ushort_t* Wvproj = Wbf + 286720;
    ushort_t* Woproj = Wbf + 352256;
    ushort_t* Wfc1   = Wbf + 417792;
    ushort_t* Wfc2   = Wbf + 679936;

    ushort_t* QKVbf = (ushort_t*)(ws + 2 * S);              // Q,K,V^T: [2S, 3.5S)
    ushort_t* O1bf  = (ushort_t*)(ws + 2 * S + 3 * S / 2);  // [3.5S, 4S)
    float* Vb   = ws + 2 * S + S / 2;                       // [2.5S, 3.5S)
    float* OffB = ws + 2 * S + 3 * S / 2;                   // [3.5S, 3.75S)
    float* AwB  = OffB + (size_t)BNq * 64;                  // [3.75S, 3.875S)
    ushort_t* Sbbf = (ushort_t*)(AwB + (size_t)BNq * 32);   // [3.875S, 4.375S)
    ushort_t* Valbf = (ushort_t*)(ws + 9 * S / 2);          // [4.5S, 5S)

    auto fp = [&](int i) { return (const float*)d_in[i]; };
    const float* x_in = fp(0);

    // ---- all fp32->bf16 casts in one dispatch ----
    CastArgs ca;
    ca.s[0] = {fp(9),  Wqkv,   192, 196608};
    ca.s[1] = {fp(10), Wproj,  64,  65536};
    ca.s[2] = {fp(12), Woff,   16,  16384};
    ca.s[3] = {fp(14), Waw,    8,   8192};
    ca.s[4] = {fp(16), Wvproj, 64,  65536};
    ca.s[5] = {fp(18), Woproj, 64,  65536};
    ca.s[6] = {fp(20), Wfc1,   256, 262144};
    ca.s[7] = {fp(22), Wfc2,   256, 262144};
    ca.s[8] = {fp(2),  Valbf,  4096, (int)S};
    castm<<<5016, 256, 0, stream>>>(ca);

    // ---- stage 1: self-attention ----
    ln_kernel<<<BNq / 4, 256, 0, stream>>>(x_in, fp(3), fp(4), Ybf);
    mgemm<1, false, false, 256><<<dim3(128, 12), 256, 0, stream>>>(
        Ybf, Wqkv, nullptr, nullptr, QKVbf, BNq, 768);
    attn_mfma<<<dim3(128, 8), 256, 0, stream>>>(
        QKVbf, QKVbf + S, QKVbf + 2 * S, O1bf);
    mgemm<0, false, true, 256><<<dim3(128, 4), 256, 0, stream>>>(
        O1bf, Wproj, fp(11), x_in, X, BNq, 256);

    // ---- stage 2: deformable attention ----
    ln_kernel<<<BNq / 4, 256, 0, stream>>>(X, fp(5), fp(6), Ybf);
    mgemm<0, false, false, 256><<<dim3(128, 4), 256, 0, stream>>>(
        Valbf, Wvproj, fp(17), nullptr, Vb, BNq, 256);
    mgemm<3, false, false, 256><<<dim3(128, 2), 256, 0, stream>>>(
        Ybf, Woff, fp(13), fp(15), OffB, BNq, 96);
    deform_kernel<<<BNq, 256, 0, stream>>>(fp(1), OffB, AwB, Vb, Sbbf);
    mgemm<0, false, true, 256><<<dim3(128, 4), 256, 0, stream>>>(
        Sbbf, Woproj, fp(19), X, X, BNq, 256);

    // ---- stage 3: MLP (fused fc1+gelu+fc2+residual; H stays in LDS) ----
    ln_kernel<<<BNq / 4, 256, 0, stream>>>(X, fp(7), fp(8), Ybf);
    mlp_fused<<<BNq / 64, 256, 0, stream>>>(
        Ybf, Wfc1, fp(21), Wfc2, fp(23), X, (float*)d_out);
}